// Round 19
// baseline (362.859 us; speedup 1.0000x reference)
//
#include <hip/hip_runtime.h>

#define ND 32
#define ED 8
#define NL 4
#define NG 1000
#define NBC_MAX 512   // max coarse buckets (N/256)
#define CHUNK 8192    // edges per k_binA block
#define CHUNK_H 4096  // edges per k_chist block

typedef unsigned short u16;

// XCD-contiguous swizzle: blocks on XCD (b%8) get a contiguous work range.
__device__ __forceinline__ int xcd_swizzle(int b, int nb) {
  int per = nb >> 3;
  return (b < (per << 3)) ? ((b & 7) * per + (b >> 3)) : b;
}

// ---------- bf16 helpers (storage bf16, compute fp32) ----------

__device__ __forceinline__ u16 f2bf(float f) {
  unsigned u = __float_as_uint(f);
  u += 0x7fffu + ((u >> 16) & 1u);  // round-to-nearest-even
  return (u16)(u >> 16);
}
__device__ __forceinline__ unsigned pack2(float a, float b) {
  return (unsigned)f2bf(a) | ((unsigned)f2bf(b) << 16);
}
__device__ __forceinline__ void cvt8(uint4 p, float* o) {
  o[0] = __uint_as_float(p.x << 16); o[1] = __uint_as_float(p.x & 0xffff0000u);
  o[2] = __uint_as_float(p.y << 16); o[3] = __uint_as_float(p.y & 0xffff0000u);
  o[4] = __uint_as_float(p.z << 16); o[5] = __uint_as_float(p.z & 0xffff0000u);
  o[6] = __uint_as_float(p.w << 16); o[7] = __uint_as_float(p.w & 0xffff0000u);
}
__device__ __forceinline__ uint4 pack8(const float* v) {
  uint4 o;
  o.x = pack2(v[0], v[1]); o.y = pack2(v[2], v[3]);
  o.z = pack2(v[4], v[5]); o.w = pack2(v[6], v[7]);
  return o;
}

// ---------- init: h = x@Wn+bn; zs/zd projections for layer-0 edge MLP ----------

__global__ void k_init_h(const float* __restrict__ x,
                         const float* __restrict__ W,   // [2][ND]
                         const float* __restrict__ b,   // [ND]
                         const float* __restrict__ We,  // [72][ED] layer 0
                         const float* __restrict__ be,  // [ED] layer 0
                         u16* __restrict__ h,
                         u16* __restrict__ zs, u16* __restrict__ zd,
                         int N) {
  int n = xcd_swizzle(blockIdx.x, gridDim.x) * blockDim.x + threadIdx.x;
  if (n >= N) return;
  float x0 = x[2 * n], x1 = x[2 * n + 1];
  float v[ND];
#pragma unroll
  for (int d = 0; d < ND; ++d) v[d] = fmaf(x0, W[d], fmaf(x1, W[ND + d], b[d]));
#pragma unroll
  for (int d = 0; d < ND; ++d) v[d] = __uint_as_float((unsigned)f2bf(v[d]) << 16);
  uint4* h4 = reinterpret_cast<uint4*>(h + (size_t)n * ND);
#pragma unroll
  for (int q = 0; q < 4; ++q) h4[q] = pack8(&v[q * 8]);
  float zsv[ED], zdv[ED];
#pragma unroll
  for (int j = 0; j < ED; ++j) { zsv[j] = 0.0f; zdv[j] = be[j]; }
#pragma unroll
  for (int k = 0; k < ND; ++k)
#pragma unroll
    for (int j = 0; j < ED; ++j) {
      zsv[j] = fmaf(v[k], We[k * ED + j], zsv[j]);
      zdv[j] = fmaf(v[k], We[(ND + k) * ED + j], zdv[j]);
    }
  *reinterpret_cast<uint4*>(zs + (size_t)n * ED) = pack8(zsv);
  *reinterpret_cast<uint4*>(zd + (size_t)n * ED) = pack8(zdv);
}

// ---------- CSR-free binned counting sort by dst ----------

__global__ void k_chist(const int* __restrict__ dst, int* __restrict__ bcnt,
                        int E, int nbc) {
  __shared__ int lcnt[NBC_MAX];
  for (int b = threadIdx.x; b < nbc; b += blockDim.x) lcnt[b] = 0;
  __syncthreads();
  int e0 = blockIdx.x * CHUNK_H;
  int e1 = min(e0 + CHUNK_H, E);
  for (int i = e0 + threadIdx.x; i < e1; i += blockDim.x)
    atomicAdd(&lcnt[dst[i] >> 8], 1);
  __syncthreads();
  for (int b = threadIdx.x; b < nbc; b += blockDim.x)
    if (lcnt[b]) atomicAdd(&bcnt[b], lcnt[b]);
}

__global__ void k_cscan(const int* __restrict__ bcnt, int* __restrict__ bbase,
                        int nbc) {
  __shared__ int s[NBC_MAX];
  int tid = threadIdx.x;
  if (nbc <= NBC_MAX) {
    int v = (tid < nbc) ? bcnt[tid] : 0;
    s[tid] = v;
    __syncthreads();
    for (int st = 1; st < NBC_MAX; st <<= 1) {
      int t = (tid >= st) ? s[tid - st] : 0;
      __syncthreads();
      s[tid] += t;
      __syncthreads();
    }
    if (tid < nbc) bbase[tid] = s[tid] - v;
    if (tid == nbc - 1) bbase[nbc] = s[tid];
  } else if (tid == 0) {
    int run = 0;
    for (int i = 0; i < nbc; ++i) { bbase[i] = run; run += bcnt[i]; }
    bbase[nbc] = run;
  }
}

// packed 8-B record: .x = src | (dst_local << 24)
__global__ void k_binA(const int* __restrict__ src, const int* __restrict__ dst,
                       const float* __restrict__ ea,
                       const int* __restrict__ bbase, int* __restrict__ cursor_c,
                       uint2* __restrict__ binned, int E, int nbc) {
  __shared__ int lcnt[NBC_MAX];
  __shared__ int lbase[NBC_MAX];
  for (int b = threadIdx.x; b < nbc; b += blockDim.x) lcnt[b] = 0;
  __syncthreads();
  int e0 = blockIdx.x * CHUNK;
  int e1 = min(e0 + CHUNK, E);
  for (int i = e0 + threadIdx.x; i < e1; i += blockDim.x)
    atomicAdd(&lcnt[dst[i] >> 8], 1);
  __syncthreads();
  for (int b = threadIdx.x; b < nbc; b += blockDim.x) {
    int c = lcnt[b];
    lbase[b] = c ? (bbase[b] + atomicAdd(&cursor_c[b], c)) : 0;
  }
  __syncthreads();
  for (int i = e0 + threadIdx.x; i < e1; i += blockDim.x) {
    int d = dst[i];
    int pos = atomicAdd(&lbase[d >> 8], 1);
    binned[pos] = make_uint2((unsigned)src[i] | ((unsigned)(d & 255) << 24),
                             __float_as_uint(ea[i]));
  }
}

// Phase B: fine sort within 256-node bucket; materialize sedge {src,dst} (8B),
// layer-0 edge embedding e0 (bf16), and per-node CSR offsets noffs[].
__global__ void k_binB(const uint2* __restrict__ binned,
                       const int* __restrict__ bbase,
                       uint2* __restrict__ sedge, u16* __restrict__ e,
                       int* __restrict__ noffs,
                       const float* __restrict__ We,  // [ED]
                       const float* __restrict__ be,  // [ED]
                       int N) {
  __shared__ int hist[256];
  __shared__ int scn[256];
  int b = blockIdx.x;
  int base = bbase[b], end = bbase[b + 1];
  int node0 = b << 8;
  int nn = min(256, N - node0);
  hist[threadIdx.x] = 0;
  __syncthreads();
  for (int p = base + threadIdx.x; p < end; p += blockDim.x)
    atomicAdd(&hist[binned[p].x >> 24], 1);
  __syncthreads();
  int v = hist[threadIdx.x];
  scn[threadIdx.x] = v;
  __syncthreads();
  for (int st = 1; st < 256; st <<= 1) {
    int t = (threadIdx.x >= (unsigned)st) ? scn[threadIdx.x - st] : 0;
    __syncthreads();
    scn[threadIdx.x] += t;
    __syncthreads();
  }
  int excl = base + scn[threadIdx.x] - v;
  if ((int)threadIdx.x < nn) noffs[node0 + threadIdx.x] = excl;  // CSR start
  if (threadIdx.x == 0) noffs[min(node0 + 256, N)] = end;        // terminator
  hist[threadIdx.x] = excl;  // running cursor
  __syncthreads();
  for (int p = base + threadIdx.x; p < end; p += blockDim.x) {
    uint2 rec = binned[p];  // L2-hot re-read
    int dl = (int)(rec.x >> 24);
    int pos = atomicAdd(&hist[dl], 1);
    sedge[pos] = make_uint2(rec.x & 0xffffffu, (unsigned)(node0 + dl));
    float a = __uint_as_float(rec.y);
    float e0[ED];
#pragma unroll
    for (int j = 0; j < ED; ++j) e0[j] = fmaf(a, We[j], be[j]);
    *reinterpret_cast<uint4*>(e + (size_t)pos * ED) = pack8(e0);
  }
}

// ---------- layer kernels ----------

// edge MLP via precomputed projections — pure streaming, no scan/atomics:
// ne = relu(zs[src]+zd[dst]+e@W3); e += ne (skipped on last layer)
template <bool LAST>
__global__ void k_edge(const u16* __restrict__ zs,
                       const u16* __restrict__ zd,
                       u16* __restrict__ e,
                       u16* __restrict__ ne,
                       const uint2* __restrict__ sedge,
                       const float* __restrict__ W3,  // [ED][ED]
                       int E) {
  int i = xcd_swizzle(blockIdx.x, gridDim.x) * blockDim.x + threadIdx.x;
  if (i >= E) return;
  uint2 sd = sedge[i];
  float zsv[ED], zdv[ED], ein[ED], acc[ED];
  cvt8(*reinterpret_cast<const uint4*>(zs + (size_t)sd.x * ED), zsv);
  cvt8(*reinterpret_cast<const uint4*>(zd + (size_t)sd.y * ED), zdv);
  cvt8(*reinterpret_cast<const uint4*>(e + (size_t)i * ED), ein);
#pragma unroll
  for (int j = 0; j < ED; ++j) acc[j] = zsv[j] + zdv[j];
#pragma unroll
  for (int k = 0; k < ED; ++k)
#pragma unroll
    for (int j = 0; j < ED; ++j)
      acc[j] = fmaf(ein[k], W3[k * ED + j], acc[j]);
#pragma unroll
  for (int j = 0; j < ED; ++j) acc[j] = fmaxf(acc[j], 0.0f);
  *reinterpret_cast<uint4*>(ne + (size_t)i * ED) = pack8(acc);
  if (!LAST) {
    float eo[ED];
#pragma unroll
    for (int j = 0; j < ED; ++j) eo[j] = ein[j] + acc[j];
    *reinterpret_cast<uint4*>(e + (size_t)i * ED) = pack8(eo);
  }
}

// node MLP, 2 threads/node: lane pair (2n,2n+1) splits the ne segment
// interleaved, combines agg via one shfl_xor, then both lanes redundantly run
// the full MLP with UNIFORM (SGPR) weights; stores are split between lanes.
template <bool PROJ>
__global__ void k_node(u16* __restrict__ h,
                       const u16* __restrict__ ne,
                       const int* __restrict__ noffs,
                       const float* __restrict__ W,     // [(ND+ED)][ND]
                       const float* __restrict__ b,     // [ND]
                       const float* __restrict__ Wen,   // [72][ED] next layer
                       const float* __restrict__ ben,   // [ED] next layer
                       u16* __restrict__ zs, u16* __restrict__ zd,
                       int N) {
  int t = xcd_swizzle(blockIdx.x, gridDim.x) * blockDim.x + threadIdx.x;
  int n = t >> 1, half = t & 1;
  if (n >= N) return;
  int o0 = noffs[n], o1 = noffs[n + 1];
  float av[ED];
#pragma unroll
  for (int j = 0; j < ED; ++j) av[j] = 0.0f;
  int p = o0 + half;
  // this lane takes every other row; keep two loads in flight
  for (; p + 2 < o1; p += 4) {
    uint4 r0 = *reinterpret_cast<const uint4*>(ne + (size_t)p * ED);
    uint4 r1 = *reinterpret_cast<const uint4*>(ne + (size_t)(p + 2) * ED);
    float t0[ED], t1[ED];
    cvt8(r0, t0); cvt8(r1, t1);
#pragma unroll
    for (int j = 0; j < ED; ++j) av[j] += t0[j] + t1[j];
  }
  for (; p < o1; p += 2) {
    float tr[ED];
    cvt8(*reinterpret_cast<const uint4*>(ne + (size_t)p * ED), tr);
#pragma unroll
    for (int j = 0; j < ED; ++j) av[j] += tr[j];
  }
  // combine the lane pair (pairs never straddle a wave boundary)
#pragma unroll
  for (int j = 0; j < ED; ++j) av[j] += __shfl_xor(av[j], 1, 64);
  float acc[ND];
#pragma unroll
  for (int j = 0; j < ND; ++j) acc[j] = b[j];
  uint4* h4 = reinterpret_cast<uint4*>(h + (size_t)n * ND);
  float hv[ND];
#pragma unroll
  for (int q = 0; q < 4; ++q) cvt8(h4[q], &hv[q * 8]);
#pragma unroll
  for (int k = 0; k < ND; ++k)
#pragma unroll
    for (int j = 0; j < ND; ++j) acc[j] = fmaf(hv[k], W[k * ND + j], acc[j]);
#pragma unroll
  for (int k = 0; k < ED; ++k)
#pragma unroll
    for (int j = 0; j < ND; ++j) acc[j] = fmaf(av[k], W[(ND + k) * ND + j], acc[j]);
  float hn[ND];
#pragma unroll
  for (int k = 0; k < ND; ++k) {
    float o = hv[k] + fmaxf(acc[k], 0.0f);
    hn[k] = __uint_as_float((unsigned)f2bf(o) << 16);  // round as stored
  }
  // split the 64B h store between the two lanes
#pragma unroll
  for (int q = 0; q < 2; ++q) h4[half * 2 + q] = pack8(&hn[(half * 2 + q) * 8]);
  if (PROJ) {
    // both lanes compute both projections (uniform weights); split stores
    float zsv[ED], zdv[ED];
#pragma unroll
    for (int j = 0; j < ED; ++j) { zsv[j] = 0.0f; zdv[j] = ben[j]; }
#pragma unroll
    for (int k = 0; k < ND; ++k)
#pragma unroll
      for (int j = 0; j < ED; ++j) {
        zsv[j] = fmaf(hn[k], Wen[k * ED + j], zsv[j]);
        zdv[j] = fmaf(hn[k], Wen[(ND + k) * ED + j], zdv[j]);
      }
    if (half == 0)
      *reinterpret_cast<uint4*>(zs + (size_t)n * ED) = pack8(zsv);
    else
      *reinterpret_cast<uint4*>(zd + (size_t)n * ED) = pack8(zdv);
  }
}

// ---------- readout ----------

__device__ __forceinline__ unsigned int enc_f32(float f) {
  unsigned int bits = __float_as_uint(f);
  return (bits & 0x80000000u) ? ~bits : (bits | 0x80000000u);
}
__device__ __forceinline__ float dec_f32(unsigned int u) {
  unsigned int bits = (u & 0x80000000u) ? (u ^ 0x80000000u) : ~u;
  return __uint_as_float(bits);
}

__global__ void k_logits(const u16* __restrict__ h,
                         const int* __restrict__ cand,
                         const int* __restrict__ batch,
                         const float* __restrict__ Wout,  // [ND]
                         const float* __restrict__ bout,  // [1]
                         float* __restrict__ logits,
                         int* __restrict__ seg,
                         unsigned int* __restrict__ mxu,  // pre-zeroed
                         int NC) {
  int c = blockIdx.x * blockDim.x + threadIdx.x;
  if (c >= NC) return;
  int idx = cand[c];
  const uint4* hr = reinterpret_cast<const uint4*>(h + (size_t)idx * ND);
  float acc = bout[0];
  float v[8];
#pragma unroll
  for (int q = 0; q < 4; ++q) {
    cvt8(hr[q], v);
#pragma unroll
    for (int k = 0; k < 8; ++k) acc = fmaf(v[k], Wout[q * 8 + k], acc);
  }
  logits[c] = acc;
  int g = batch[idx];
  seg[c] = g;
  atomicMax(&mxu[g], enc_f32(acc));
}

__global__ void k_expsum(float* __restrict__ logits,
                         const int* __restrict__ seg,
                         const unsigned int* __restrict__ mxu,
                         float* __restrict__ sum,  // pre-zeroed
                         int NC) {
  int c = blockIdx.x * blockDim.x + threadIdx.x;
  if (c >= NC) return;
  int g = seg[c];
  float sh = logits[c] - dec_f32(mxu[g]);
  logits[c] = sh;
  atomicAdd(&sum[g], expf(sh));
}

__global__ void k_final(const float* __restrict__ shifted,
                        const int* __restrict__ seg,
                        const float* __restrict__ sum,
                        float* __restrict__ out, int NC) {
  int c = blockIdx.x * blockDim.x + threadIdx.x;
  if (c >= NC) return;
  out[c] = shifted[c] - logf(sum[seg[c]]);
}

// ---------- launch ----------

extern "C" void kernel_launch(void* const* d_in, const int* in_sizes, int n_in,
                              void* d_out, int out_size, void* d_ws, size_t ws_size,
                              hipStream_t stream) {
  const float* x       = (const float*)d_in[0];
  const float* ea      = (const float*)d_in[1];
  const float* Wn_in   = (const float*)d_in[2];
  const float* bn_in   = (const float*)d_in[3];
  const float* We_in   = (const float*)d_in[4];
  const float* be_in   = (const float*)d_in[5];
  const float* We_l    = (const float*)d_in[6];
  const float* be_l    = (const float*)d_in[7];
  const float* Wn_l    = (const float*)d_in[8];
  const float* bn_l    = (const float*)d_in[9];
  const float* Wout    = (const float*)d_in[10];
  const float* bout    = (const float*)d_in[11];
  const int* edge_index= (const int*)d_in[12];
  const int* batch     = (const int*)d_in[13];
  const int* cand      = (const int*)d_in[14];

  const int N  = in_sizes[13];
  const int E  = in_sizes[1];
  const int NC = in_sizes[14];
  const int nbc = (N + 255) >> 8;

  char* ws = (char*)d_ws;
  uint2* binned = (uint2*)ws; ws += (size_t)E * sizeof(uint2);
  uint2* sedge  = (uint2*)ws; ws += (size_t)E * sizeof(uint2);
  u16*   h      = (u16*)ws;   ws += (size_t)N * ND * sizeof(u16);
  u16*   e      = (u16*)ws;   ws += (size_t)E * ED * sizeof(u16);
  u16*   ne     = (u16*)ws;   ws += (size_t)E * ED * sizeof(u16);
  u16*   zs     = (u16*)ws;   ws += (size_t)N * ED * sizeof(u16);
  u16*   zd     = (u16*)ws;   ws += (size_t)N * ED * sizeof(u16);
  int*   noffs  = (int*)ws;   ws += ((size_t)N + 4) * sizeof(int);
  int*   bcnt   = (int*)ws;   ws += (size_t)NBC_MAX * sizeof(int);   // contiguous
  int*   cursor = (int*)ws;   ws += (size_t)NBC_MAX * sizeof(int);   // with bcnt
  int*   bbase  = (int*)ws;   ws += ((size_t)NBC_MAX + 4) * sizeof(int);
  float* logits = (float*)ws; ws += (size_t)NC * sizeof(float);
  int*   seg    = (int*)ws;   ws += (size_t)NC * sizeof(int);
  unsigned int* mxu = (unsigned int*)ws; ws += (size_t)NG * sizeof(unsigned int);
  float* sum    = (float*)ws; ws += (size_t)NG * sizeof(float);  // contiguous w/ mxu

  const int* srcp = edge_index;
  const int* dstp = edge_index + E;
  const int blk = 256;
  const size_t WE_STRIDE = (size_t)(2 * ND + ED) * ED;  // 72*8

  // binned two-phase counting sort (8-B packed records) + e0 + CSR offsets
  hipMemsetAsync(bcnt, 0, 2 * (size_t)NBC_MAX * sizeof(int), stream);  // bcnt+cursor
  k_chist<<<(E + CHUNK_H - 1) / CHUNK_H, 1024, 0, stream>>>(dstp, bcnt, E, nbc);
  k_cscan<<<1, NBC_MAX, 0, stream>>>(bcnt, bbase, nbc);
  k_binA<<<(E + CHUNK - 1) / CHUNK, 1024, 0, stream>>>(srcp, dstp, ea, bbase,
                                                       cursor, binned, E, nbc);
  k_binB<<<nbc, 256, 0, stream>>>(binned, bbase, sedge, e, noffs, We_in, be_in, N);

  k_init_h<<<(N + blk - 1) / blk, blk, 0, stream>>>(x, Wn_in, bn_in, We_l, be_l,
                                                    h, zs, zd, N);

  const int egrid = (E + blk - 1) / blk;
  const int ngrid2 = ((size_t)N * 2 + blk - 1) / blk;
  for (int l = 0; l < NL; ++l) {
    const float* W3 = We_l + l * WE_STRIDE + (size_t)2 * ND * ED;
    const float* Wn = Wn_l + (size_t)l * (ND + ED) * ND;
    const float* bn = bn_l + (size_t)l * ND;
    if (l + 1 < NL) {
      k_edge<false><<<egrid, blk, 0, stream>>>(zs, zd, e, ne, sedge, W3, E);
      k_node<true><<<ngrid2, blk, 0, stream>>>(
          h, ne, noffs, Wn, bn, We_l + (l + 1) * WE_STRIDE,
          be_l + (size_t)(l + 1) * ED, zs, zd, N);
    } else {
      k_edge<true><<<egrid, blk, 0, stream>>>(zs, zd, e, ne, sedge, W3, E);
      k_node<false><<<ngrid2, blk, 0, stream>>>(
          h, ne, noffs, Wn, bn, nullptr, nullptr, nullptr, nullptr, N);
    }
  }

  hipMemsetAsync(mxu, 0, NG * (sizeof(unsigned int) + sizeof(float)), stream);
  k_logits<<<(NC + blk - 1) / blk, blk, 0, stream>>>(h, cand, batch, Wout, bout,
                                                     logits, seg, mxu, NC);
  k_expsum<<<(NC + blk - 1) / blk, blk, 0, stream>>>(logits, seg, mxu, sum, NC);
  k_final<<<(NC + blk - 1) / blk, blk, 0, stream>>>(logits, seg, sum,
                                                    (float*)d_out, NC);
}

// Round 20
// 351.964 us; speedup vs baseline: 1.0310x; 1.0310x over previous
//
#include <hip/hip_runtime.h>

#define ND 32
#define ED 8
#define NL 4
#define NG 1000
#define NBC_MAX 512   // max coarse buckets (N/256)
#define CHUNK 8192    // edges per k_binA block
#define CHUNK_H 4096  // edges per k_chist block
#define NBLK 64       // block size for node-grid kernels (load balance)

typedef unsigned short u16;

// XCD-contiguous swizzle: blocks on XCD (b%8) get a contiguous work range.
__device__ __forceinline__ int xcd_swizzle(int b, int nb) {
  int per = nb >> 3;
  return (b < (per << 3)) ? ((b & 7) * per + (b >> 3)) : b;
}

// ---------- bf16 helpers (storage bf16, compute fp32) ----------

__device__ __forceinline__ u16 f2bf(float f) {
  unsigned u = __float_as_uint(f);
  u += 0x7fffu + ((u >> 16) & 1u);  // round-to-nearest-even
  return (u16)(u >> 16);
}
__device__ __forceinline__ unsigned pack2(float a, float b) {
  return (unsigned)f2bf(a) | ((unsigned)f2bf(b) << 16);
}
__device__ __forceinline__ void cvt8(uint4 p, float* o) {
  o[0] = __uint_as_float(p.x << 16); o[1] = __uint_as_float(p.x & 0xffff0000u);
  o[2] = __uint_as_float(p.y << 16); o[3] = __uint_as_float(p.y & 0xffff0000u);
  o[4] = __uint_as_float(p.z << 16); o[5] = __uint_as_float(p.z & 0xffff0000u);
  o[6] = __uint_as_float(p.w << 16); o[7] = __uint_as_float(p.w & 0xffff0000u);
}
__device__ __forceinline__ uint4 pack8(const float* v) {
  uint4 o;
  o.x = pack2(v[0], v[1]); o.y = pack2(v[2], v[3]);
  o.z = pack2(v[4], v[5]); o.w = pack2(v[6], v[7]);
  return o;
}

// ---------- init: h = x@Wn+bn; zs/zd projections for layer-0 edge MLP ----------

__global__ void k_init_h(const float* __restrict__ x,
                         const float* __restrict__ W,   // [2][ND]
                         const float* __restrict__ b,   // [ND]
                         const float* __restrict__ We,  // [72][ED] layer 0
                         const float* __restrict__ be,  // [ED] layer 0
                         u16* __restrict__ h,
                         u16* __restrict__ zs, u16* __restrict__ zd,
                         int N) {
  int n = xcd_swizzle(blockIdx.x, gridDim.x) * blockDim.x + threadIdx.x;
  if (n >= N) return;
  float x0 = x[2 * n], x1 = x[2 * n + 1];
  float v[ND];
#pragma unroll
  for (int d = 0; d < ND; ++d) v[d] = fmaf(x0, W[d], fmaf(x1, W[ND + d], b[d]));
#pragma unroll
  for (int d = 0; d < ND; ++d) v[d] = __uint_as_float((unsigned)f2bf(v[d]) << 16);
  uint4* h4 = reinterpret_cast<uint4*>(h + (size_t)n * ND);
#pragma unroll
  for (int q = 0; q < 4; ++q) h4[q] = pack8(&v[q * 8]);
  float zsv[ED], zdv[ED];
#pragma unroll
  for (int j = 0; j < ED; ++j) { zsv[j] = 0.0f; zdv[j] = be[j]; }
#pragma unroll
  for (int k = 0; k < ND; ++k)
#pragma unroll
    for (int j = 0; j < ED; ++j) {
      zsv[j] = fmaf(v[k], We[k * ED + j], zsv[j]);
      zdv[j] = fmaf(v[k], We[(ND + k) * ED + j], zdv[j]);
    }
  *reinterpret_cast<uint4*>(zs + (size_t)n * ED) = pack8(zsv);
  *reinterpret_cast<uint4*>(zd + (size_t)n * ED) = pack8(zdv);
}

// ---------- CSR-free binned counting sort by dst ----------

__global__ void k_chist(const int* __restrict__ dst, int* __restrict__ bcnt,
                        int E, int nbc) {
  __shared__ int lcnt[NBC_MAX];
  for (int b = threadIdx.x; b < nbc; b += blockDim.x) lcnt[b] = 0;
  __syncthreads();
  int e0 = blockIdx.x * CHUNK_H;
  int e1 = min(e0 + CHUNK_H, E);
  for (int i = e0 + threadIdx.x; i < e1; i += blockDim.x)
    atomicAdd(&lcnt[dst[i] >> 8], 1);
  __syncthreads();
  for (int b = threadIdx.x; b < nbc; b += blockDim.x)
    if (lcnt[b]) atomicAdd(&bcnt[b], lcnt[b]);
}

__global__ void k_cscan(const int* __restrict__ bcnt, int* __restrict__ bbase,
                        int nbc) {
  __shared__ int s[NBC_MAX];
  int tid = threadIdx.x;
  if (nbc <= NBC_MAX) {
    int v = (tid < nbc) ? bcnt[tid] : 0;
    s[tid] = v;
    __syncthreads();
    for (int st = 1; st < NBC_MAX; st <<= 1) {
      int t = (tid >= st) ? s[tid - st] : 0;
      __syncthreads();
      s[tid] += t;
      __syncthreads();
    }
    if (tid < nbc) bbase[tid] = s[tid] - v;
    if (tid == nbc - 1) bbase[nbc] = s[tid];
  } else if (tid == 0) {
    int run = 0;
    for (int i = 0; i < nbc; ++i) { bbase[i] = run; run += bcnt[i]; }
    bbase[nbc] = run;
  }
}

// packed 8-B record: .x = src | (dst_local << 24)
__global__ void k_binA(const int* __restrict__ src, const int* __restrict__ dst,
                       const float* __restrict__ ea,
                       const int* __restrict__ bbase, int* __restrict__ cursor_c,
                       uint2* __restrict__ binned, int E, int nbc) {
  __shared__ int lcnt[NBC_MAX];
  __shared__ int lbase[NBC_MAX];
  for (int b = threadIdx.x; b < nbc; b += blockDim.x) lcnt[b] = 0;
  __syncthreads();
  int e0 = blockIdx.x * CHUNK;
  int e1 = min(e0 + CHUNK, E);
  for (int i = e0 + threadIdx.x; i < e1; i += blockDim.x)
    atomicAdd(&lcnt[dst[i] >> 8], 1);
  __syncthreads();
  for (int b = threadIdx.x; b < nbc; b += blockDim.x) {
    int c = lcnt[b];
    lbase[b] = c ? (bbase[b] + atomicAdd(&cursor_c[b], c)) : 0;
  }
  __syncthreads();
  for (int i = e0 + threadIdx.x; i < e1; i += blockDim.x) {
    int d = dst[i];
    int pos = atomicAdd(&lbase[d >> 8], 1);
    binned[pos] = make_uint2((unsigned)src[i] | ((unsigned)(d & 255) << 24),
                             __float_as_uint(ea[i]));
  }
}

// Phase B: fine sort within 256-node bucket; materialize sedge {src,dst} (8B),
// layer-0 edge embedding e0 (bf16), and per-node CSR offsets noffs[].
__global__ void k_binB(const uint2* __restrict__ binned,
                       const int* __restrict__ bbase,
                       uint2* __restrict__ sedge, u16* __restrict__ e,
                       int* __restrict__ noffs,
                       const float* __restrict__ We,  // [ED]
                       const float* __restrict__ be,  // [ED]
                       int N) {
  __shared__ int hist[256];
  __shared__ int scn[256];
  int b = blockIdx.x;
  int base = bbase[b], end = bbase[b + 1];
  int node0 = b << 8;
  int nn = min(256, N - node0);
  hist[threadIdx.x] = 0;
  __syncthreads();
  for (int p = base + threadIdx.x; p < end; p += blockDim.x)
    atomicAdd(&hist[binned[p].x >> 24], 1);
  __syncthreads();
  int v = hist[threadIdx.x];
  scn[threadIdx.x] = v;
  __syncthreads();
  for (int st = 1; st < 256; st <<= 1) {
    int t = (threadIdx.x >= (unsigned)st) ? scn[threadIdx.x - st] : 0;
    __syncthreads();
    scn[threadIdx.x] += t;
    __syncthreads();
  }
  int excl = base + scn[threadIdx.x] - v;
  if ((int)threadIdx.x < nn) noffs[node0 + threadIdx.x] = excl;  // CSR start
  if (threadIdx.x == 0) noffs[min(node0 + 256, N)] = end;        // terminator
  hist[threadIdx.x] = excl;  // running cursor
  __syncthreads();
  for (int p = base + threadIdx.x; p < end; p += blockDim.x) {
    uint2 rec = binned[p];  // L2-hot re-read
    int dl = (int)(rec.x >> 24);
    int pos = atomicAdd(&hist[dl], 1);
    sedge[pos] = make_uint2(rec.x & 0xffffffu, (unsigned)(node0 + dl));
    float a = __uint_as_float(rec.y);
    float e0[ED];
#pragma unroll
    for (int j = 0; j < ED; ++j) e0[j] = fmaf(a, We[j], be[j]);
    *reinterpret_cast<uint4*>(e + (size_t)pos * ED) = pack8(e0);
  }
}

// ---------- layer kernels ----------

// edge MLP via precomputed projections — pure streaming, no scan/atomics:
// ne = relu(zs[src]+zd[dst]+e@W3); e += ne (skipped on last layer)
template <bool LAST>
__global__ void k_edge(const u16* __restrict__ zs,
                       const u16* __restrict__ zd,
                       u16* __restrict__ e,
                       u16* __restrict__ ne,
                       const uint2* __restrict__ sedge,
                       const float* __restrict__ W3,  // [ED][ED]
                       int E) {
  int i = xcd_swizzle(blockIdx.x, gridDim.x) * blockDim.x + threadIdx.x;
  if (i >= E) return;
  uint2 sd = sedge[i];
  float zsv[ED], zdv[ED], ein[ED], acc[ED];
  cvt8(*reinterpret_cast<const uint4*>(zs + (size_t)sd.x * ED), zsv);
  cvt8(*reinterpret_cast<const uint4*>(zd + (size_t)sd.y * ED), zdv);
  cvt8(*reinterpret_cast<const uint4*>(e + (size_t)i * ED), ein);
#pragma unroll
  for (int j = 0; j < ED; ++j) acc[j] = zsv[j] + zdv[j];
#pragma unroll
  for (int k = 0; k < ED; ++k)
#pragma unroll
    for (int j = 0; j < ED; ++j)
      acc[j] = fmaf(ein[k], W3[k * ED + j], acc[j]);
#pragma unroll
  for (int j = 0; j < ED; ++j) acc[j] = fmaxf(acc[j], 0.0f);
  *reinterpret_cast<uint4*>(ne + (size_t)i * ED) = pack8(acc);
  if (!LAST) {
    float eo[ED];
#pragma unroll
    for (int j = 0; j < ED; ++j) eo[j] = ein[j] + acc[j];
    *reinterpret_cast<uint4*>(e + (size_t)i * ED) = pack8(eo);
  }
}

// node MLP: agg = sum of this node's CSR segment of ne (contiguous, 4-wide
// independent loads in flight); h += relu([h, agg]@W + b); emits next-layer
// zs/zd. Weights uniform (SGPR broadcast). 64-thread blocks for load balance.
template <bool PROJ>
__global__ void k_node(u16* __restrict__ h,
                       const u16* __restrict__ ne,
                       const int* __restrict__ noffs,
                       const float* __restrict__ W,     // [(ND+ED)][ND]
                       const float* __restrict__ b,     // [ND]
                       const float* __restrict__ Wen,   // [72][ED] next layer
                       const float* __restrict__ ben,   // [ED] next layer
                       u16* __restrict__ zs, u16* __restrict__ zd,
                       int N) {
  int n = xcd_swizzle(blockIdx.x, gridDim.x) * blockDim.x + threadIdx.x;
  if (n >= N) return;
  int o0 = noffs[n], o1 = noffs[n + 1];
  float av[ED];
#pragma unroll
  for (int j = 0; j < ED; ++j) av[j] = 0.0f;
  int p = o0;
  // 4 independent loads in flight per iteration
  for (; p + 3 < o1; p += 4) {
    uint4 r0 = *reinterpret_cast<const uint4*>(ne + (size_t)(p + 0) * ED);
    uint4 r1 = *reinterpret_cast<const uint4*>(ne + (size_t)(p + 1) * ED);
    uint4 r2 = *reinterpret_cast<const uint4*>(ne + (size_t)(p + 2) * ED);
    uint4 r3 = *reinterpret_cast<const uint4*>(ne + (size_t)(p + 3) * ED);
    float t0[ED], t1[ED], t2[ED], t3[ED];
    cvt8(r0, t0); cvt8(r1, t1); cvt8(r2, t2); cvt8(r3, t3);
#pragma unroll
    for (int j = 0; j < ED; ++j)
      av[j] += (t0[j] + t1[j]) + (t2[j] + t3[j]);
  }
  for (; p < o1; ++p) {
    float t[ED];
    cvt8(*reinterpret_cast<const uint4*>(ne + (size_t)p * ED), t);
#pragma unroll
    for (int j = 0; j < ED; ++j) av[j] += t[j];
  }
  float acc[ND];
#pragma unroll
  for (int j = 0; j < ND; ++j) acc[j] = b[j];
  uint4* h4 = reinterpret_cast<uint4*>(h + (size_t)n * ND);
  float hv[ND];
#pragma unroll
  for (int q = 0; q < 4; ++q) cvt8(h4[q], &hv[q * 8]);
#pragma unroll
  for (int k = 0; k < ND; ++k)
#pragma unroll
    for (int j = 0; j < ND; ++j) acc[j] = fmaf(hv[k], W[k * ND + j], acc[j]);
#pragma unroll
  for (int k = 0; k < ED; ++k)
#pragma unroll
    for (int j = 0; j < ND; ++j) acc[j] = fmaf(av[k], W[(ND + k) * ND + j], acc[j]);
  float hn[ND];
#pragma unroll
  for (int k = 0; k < ND; ++k) {
    float o = hv[k] + fmaxf(acc[k], 0.0f);
    hn[k] = __uint_as_float((unsigned)f2bf(o) << 16);  // round as stored
  }
#pragma unroll
  for (int q = 0; q < 4; ++q) h4[q] = pack8(&hn[q * 8]);
  if (PROJ) {
    float zsv[ED], zdv[ED];
#pragma unroll
    for (int j = 0; j < ED; ++j) { zsv[j] = 0.0f; zdv[j] = ben[j]; }
#pragma unroll
    for (int k = 0; k < ND; ++k)
#pragma unroll
      for (int j = 0; j < ED; ++j) {
        zsv[j] = fmaf(hn[k], Wen[k * ED + j], zsv[j]);
        zdv[j] = fmaf(hn[k], Wen[(ND + k) * ED + j], zdv[j]);
      }
    *reinterpret_cast<uint4*>(zs + (size_t)n * ED) = pack8(zsv);
    *reinterpret_cast<uint4*>(zd + (size_t)n * ED) = pack8(zdv);
  }
}

// ---------- readout ----------

__device__ __forceinline__ unsigned int enc_f32(float f) {
  unsigned int bits = __float_as_uint(f);
  return (bits & 0x80000000u) ? ~bits : (bits | 0x80000000u);
}
__device__ __forceinline__ float dec_f32(unsigned int u) {
  unsigned int bits = (u & 0x80000000u) ? (u ^ 0x80000000u) : ~u;
  return __uint_as_float(bits);
}

__global__ void k_logits(const u16* __restrict__ h,
                         const int* __restrict__ cand,
                         const int* __restrict__ batch,
                         const float* __restrict__ Wout,  // [ND]
                         const float* __restrict__ bout,  // [1]
                         float* __restrict__ logits,
                         int* __restrict__ seg,
                         unsigned int* __restrict__ mxu,  // pre-zeroed
                         int NC) {
  int c = blockIdx.x * blockDim.x + threadIdx.x;
  if (c >= NC) return;
  int idx = cand[c];
  const uint4* hr = reinterpret_cast<const uint4*>(h + (size_t)idx * ND);
  float acc = bout[0];
  float v[8];
#pragma unroll
  for (int q = 0; q < 4; ++q) {
    cvt8(hr[q], v);
#pragma unroll
    for (int k = 0; k < 8; ++k) acc = fmaf(v[k], Wout[q * 8 + k], acc);
  }
  logits[c] = acc;
  int g = batch[idx];
  seg[c] = g;
  atomicMax(&mxu[g], enc_f32(acc));
}

__global__ void k_expsum(float* __restrict__ logits,
                         const int* __restrict__ seg,
                         const unsigned int* __restrict__ mxu,
                         float* __restrict__ sum,  // pre-zeroed
                         int NC) {
  int c = blockIdx.x * blockDim.x + threadIdx.x;
  if (c >= NC) return;
  int g = seg[c];
  float sh = logits[c] - dec_f32(mxu[g]);
  logits[c] = sh;
  atomicAdd(&sum[g], expf(sh));
}

__global__ void k_final(const float* __restrict__ shifted,
                        const int* __restrict__ seg,
                        const float* __restrict__ sum,
                        float* __restrict__ out, int NC) {
  int c = blockIdx.x * blockDim.x + threadIdx.x;
  if (c >= NC) return;
  out[c] = shifted[c] - logf(sum[seg[c]]);
}

// ---------- launch ----------

extern "C" void kernel_launch(void* const* d_in, const int* in_sizes, int n_in,
                              void* d_out, int out_size, void* d_ws, size_t ws_size,
                              hipStream_t stream) {
  const float* x       = (const float*)d_in[0];
  const float* ea      = (const float*)d_in[1];
  const float* Wn_in   = (const float*)d_in[2];
  const float* bn_in   = (const float*)d_in[3];
  const float* We_in   = (const float*)d_in[4];
  const float* be_in   = (const float*)d_in[5];
  const float* We_l    = (const float*)d_in[6];
  const float* be_l    = (const float*)d_in[7];
  const float* Wn_l    = (const float*)d_in[8];
  const float* bn_l    = (const float*)d_in[9];
  const float* Wout    = (const float*)d_in[10];
  const float* bout    = (const float*)d_in[11];
  const int* edge_index= (const int*)d_in[12];
  const int* batch     = (const int*)d_in[13];
  const int* cand      = (const int*)d_in[14];

  const int N  = in_sizes[13];
  const int E  = in_sizes[1];
  const int NC = in_sizes[14];
  const int nbc = (N + 255) >> 8;

  char* ws = (char*)d_ws;
  uint2* binned = (uint2*)ws; ws += (size_t)E * sizeof(uint2);
  uint2* sedge  = (uint2*)ws; ws += (size_t)E * sizeof(uint2);
  u16*   h      = (u16*)ws;   ws += (size_t)N * ND * sizeof(u16);
  u16*   e      = (u16*)ws;   ws += (size_t)E * ED * sizeof(u16);
  u16*   ne     = (u16*)ws;   ws += (size_t)E * ED * sizeof(u16);
  u16*   zs     = (u16*)ws;   ws += (size_t)N * ED * sizeof(u16);
  u16*   zd     = (u16*)ws;   ws += (size_t)N * ED * sizeof(u16);
  int*   noffs  = (int*)ws;   ws += ((size_t)N + 4) * sizeof(int);
  int*   bcnt   = (int*)ws;   ws += (size_t)NBC_MAX * sizeof(int);   // contiguous
  int*   cursor = (int*)ws;   ws += (size_t)NBC_MAX * sizeof(int);   // with bcnt
  int*   bbase  = (int*)ws;   ws += ((size_t)NBC_MAX + 4) * sizeof(int);
  float* logits = (float*)ws; ws += (size_t)NC * sizeof(float);
  int*   seg    = (int*)ws;   ws += (size_t)NC * sizeof(int);
  unsigned int* mxu = (unsigned int*)ws; ws += (size_t)NG * sizeof(unsigned int);
  float* sum    = (float*)ws; ws += (size_t)NG * sizeof(float);  // contiguous w/ mxu

  const int* srcp = edge_index;
  const int* dstp = edge_index + E;
  const int blk = 256;
  const size_t WE_STRIDE = (size_t)(2 * ND + ED) * ED;  // 72*8

  // binned two-phase counting sort (8-B packed records) + e0 + CSR offsets
  hipMemsetAsync(bcnt, 0, 2 * (size_t)NBC_MAX * sizeof(int), stream);  // bcnt+cursor
  k_chist<<<(E + CHUNK_H - 1) / CHUNK_H, 1024, 0, stream>>>(dstp, bcnt, E, nbc);
  k_cscan<<<1, NBC_MAX, 0, stream>>>(bcnt, bbase, nbc);
  k_binA<<<(E + CHUNK - 1) / CHUNK, 1024, 0, stream>>>(srcp, dstp, ea, bbase,
                                                       cursor, binned, E, nbc);
  k_binB<<<nbc, 256, 0, stream>>>(binned, bbase, sedge, e, noffs, We_in, be_in, N);

  k_init_h<<<(N + NBLK - 1) / NBLK, NBLK, 0, stream>>>(x, Wn_in, bn_in, We_l,
                                                       be_l, h, zs, zd, N);

  const int egrid = (E + blk - 1) / blk;
  const int ngrid = (N + NBLK - 1) / NBLK;
  for (int l = 0; l < NL; ++l) {
    const float* W3 = We_l + l * WE_STRIDE + (size_t)2 * ND * ED;
    const float* Wn = Wn_l + (size_t)l * (ND + ED) * ND;
    const float* bn = bn_l + (size_t)l * ND;
    if (l + 1 < NL) {
      k_edge<false><<<egrid, blk, 0, stream>>>(zs, zd, e, ne, sedge, W3, E);
      k_node<true><<<ngrid, NBLK, 0, stream>>>(
          h, ne, noffs, Wn, bn, We_l + (l + 1) * WE_STRIDE,
          be_l + (size_t)(l + 1) * ED, zs, zd, N);
    } else {
      k_edge<true><<<egrid, blk, 0, stream>>>(zs, zd, e, ne, sedge, W3, E);
      k_node<false><<<ngrid, NBLK, 0, stream>>>(
          h, ne, noffs, Wn, bn, nullptr, nullptr, nullptr, nullptr, N);
    }
  }

  hipMemsetAsync(mxu, 0, NG * (sizeof(unsigned int) + sizeof(float)), stream);
  k_logits<<<(NC + blk - 1) / blk, blk, 0, stream>>>(h, cand, batch, Wout, bout,
                                                     logits, seg, mxu, NC);
  k_expsum<<<(NC + blk - 1) / blk, blk, 0, stream>>>(logits, seg, mxu, sum, NC);
  k_final<<<(NC + blk - 1) / blk, blk, 0, stream>>>(logits, seg, sum,
                                                    (float*)d_out, NC);
}

// Round 21
// 345.339 us; speedup vs baseline: 1.0507x; 1.0192x over previous
//
#include <hip/hip_runtime.h>

#define ND 32
#define ED 8
#define NL 4
#define NG 1000
#define NBC_MAX 512   // max coarse buckets (N/256)
#define CHUNK 8192    // edges per k_binA block
#define CHUNK_H 4096  // edges per k_chist block
#define NBLK 64       // block size for node-grid kernels

typedef unsigned short u16;

// XCD-contiguous swizzle: blocks on XCD (b%8) get a contiguous work range.
__device__ __forceinline__ int xcd_swizzle(int b, int nb) {
  int per = nb >> 3;
  return (b < (per << 3)) ? ((b & 7) * per + (b >> 3)) : b;
}

// ---------- bf16 helpers (storage bf16, compute fp32) ----------

__device__ __forceinline__ u16 f2bf(float f) {
  unsigned u = __float_as_uint(f);
  u += 0x7fffu + ((u >> 16) & 1u);  // round-to-nearest-even
  return (u16)(u >> 16);
}
__device__ __forceinline__ unsigned pack2(float a, float b) {
  return (unsigned)f2bf(a) | ((unsigned)f2bf(b) << 16);
}
__device__ __forceinline__ void cvt8(uint4 p, float* o) {
  o[0] = __uint_as_float(p.x << 16); o[1] = __uint_as_float(p.x & 0xffff0000u);
  o[2] = __uint_as_float(p.y << 16); o[3] = __uint_as_float(p.y & 0xffff0000u);
  o[4] = __uint_as_float(p.z << 16); o[5] = __uint_as_float(p.z & 0xffff0000u);
  o[6] = __uint_as_float(p.w << 16); o[7] = __uint_as_float(p.w & 0xffff0000u);
}
__device__ __forceinline__ uint4 pack8(const float* v) {
  uint4 o;
  o.x = pack2(v[0], v[1]); o.y = pack2(v[2], v[3]);
  o.z = pack2(v[4], v[5]); o.w = pack2(v[6], v[7]);
  return o;
}

// ---------- init: h = x@Wn+bn; zs/zd projections for layer-0 edge MLP ----------

__global__ void k_init_h(const float* __restrict__ x,
                         const float* __restrict__ W,   // [2][ND]
                         const float* __restrict__ b,   // [ND]
                         const float* __restrict__ We,  // [72][ED] layer 0
                         const float* __restrict__ be,  // [ED] layer 0
                         u16* __restrict__ h,
                         u16* __restrict__ zs, u16* __restrict__ zd,
                         int N) {
  int n = xcd_swizzle(blockIdx.x, gridDim.x) * blockDim.x + threadIdx.x;
  if (n >= N) return;
  float x0 = x[2 * n], x1 = x[2 * n + 1];
  float v[ND];
#pragma unroll
  for (int d = 0; d < ND; ++d) v[d] = fmaf(x0, W[d], fmaf(x1, W[ND + d], b[d]));
#pragma unroll
  for (int d = 0; d < ND; ++d) v[d] = __uint_as_float((unsigned)f2bf(v[d]) << 16);
  uint4* h4 = reinterpret_cast<uint4*>(h + (size_t)n * ND);
#pragma unroll
  for (int q = 0; q < 4; ++q) h4[q] = pack8(&v[q * 8]);
  float zsv[ED], zdv[ED];
#pragma unroll
  for (int j = 0; j < ED; ++j) { zsv[j] = 0.0f; zdv[j] = be[j]; }
#pragma unroll
  for (int k = 0; k < ND; ++k)
#pragma unroll
    for (int j = 0; j < ED; ++j) {
      zsv[j] = fmaf(v[k], We[k * ED + j], zsv[j]);
      zdv[j] = fmaf(v[k], We[(ND + k) * ED + j], zdv[j]);
    }
  *reinterpret_cast<uint4*>(zs + (size_t)n * ED) = pack8(zsv);
  *reinterpret_cast<uint4*>(zd + (size_t)n * ED) = pack8(zdv);
}

// ---------- CSR-free binned counting sort by dst ----------

__global__ void k_chist(const int* __restrict__ dst, int* __restrict__ bcnt,
                        int E, int nbc) {
  __shared__ int lcnt[NBC_MAX];
  for (int b = threadIdx.x; b < nbc; b += blockDim.x) lcnt[b] = 0;
  __syncthreads();
  int e0 = blockIdx.x * CHUNK_H;
  int e1 = min(e0 + CHUNK_H, E);
  for (int i = e0 + threadIdx.x; i < e1; i += blockDim.x)
    atomicAdd(&lcnt[dst[i] >> 8], 1);
  __syncthreads();
  for (int b = threadIdx.x; b < nbc; b += blockDim.x)
    if (lcnt[b]) atomicAdd(&bcnt[b], lcnt[b]);
}

__global__ void k_cscan(const int* __restrict__ bcnt, int* __restrict__ bbase,
                        int nbc) {
  __shared__ int s[NBC_MAX];
  int tid = threadIdx.x;
  if (nbc <= NBC_MAX) {
    int v = (tid < nbc) ? bcnt[tid] : 0;
    s[tid] = v;
    __syncthreads();
    for (int st = 1; st < NBC_MAX; st <<= 1) {
      int t = (tid >= st) ? s[tid - st] : 0;
      __syncthreads();
      s[tid] += t;
      __syncthreads();
    }
    if (tid < nbc) bbase[tid] = s[tid] - v;
    if (tid == nbc - 1) bbase[nbc] = s[tid];
  } else if (tid == 0) {
    int run = 0;
    for (int i = 0; i < nbc; ++i) { bbase[i] = run; run += bcnt[i]; }
    bbase[nbc] = run;
  }
}

// packed 8-B record: .x = src | (dst_local << 24)
__global__ void k_binA(const int* __restrict__ src, const int* __restrict__ dst,
                       const float* __restrict__ ea,
                       const int* __restrict__ bbase, int* __restrict__ cursor_c,
                       uint2* __restrict__ binned, int E, int nbc) {
  __shared__ int lcnt[NBC_MAX];
  __shared__ int lbase[NBC_MAX];
  for (int b = threadIdx.x; b < nbc; b += blockDim.x) lcnt[b] = 0;
  __syncthreads();
  int e0 = blockIdx.x * CHUNK;
  int e1 = min(e0 + CHUNK, E);
  for (int i = e0 + threadIdx.x; i < e1; i += blockDim.x)
    atomicAdd(&lcnt[dst[i] >> 8], 1);
  __syncthreads();
  for (int b = threadIdx.x; b < nbc; b += blockDim.x) {
    int c = lcnt[b];
    lbase[b] = c ? (bbase[b] + atomicAdd(&cursor_c[b], c)) : 0;
  }
  __syncthreads();
  for (int i = e0 + threadIdx.x; i < e1; i += blockDim.x) {
    int d = dst[i];
    int pos = atomicAdd(&lbase[d >> 8], 1);
    binned[pos] = make_uint2((unsigned)src[i] | ((unsigned)(d & 255) << 24),
                             __float_as_uint(ea[i]));
  }
}

// Phase B: fine sort within 256-node bucket; materialize sedge {src,dst} (8B),
// layer-0 edge embedding e0 (bf16), and per-node CSR offsets noffs[].
__global__ void k_binB(const uint2* __restrict__ binned,
                       const int* __restrict__ bbase,
                       uint2* __restrict__ sedge, u16* __restrict__ e,
                       int* __restrict__ noffs,
                       const float* __restrict__ We,  // [ED]
                       const float* __restrict__ be,  // [ED]
                       int N) {
  __shared__ int hist[256];
  __shared__ int scn[256];
  int b = blockIdx.x;
  int base = bbase[b], end = bbase[b + 1];
  int node0 = b << 8;
  int nn = min(256, N - node0);
  hist[threadIdx.x] = 0;
  __syncthreads();
  for (int p = base + threadIdx.x; p < end; p += blockDim.x)
    atomicAdd(&hist[binned[p].x >> 24], 1);
  __syncthreads();
  int v = hist[threadIdx.x];
  scn[threadIdx.x] = v;
  __syncthreads();
  for (int st = 1; st < 256; st <<= 1) {
    int t = (threadIdx.x >= (unsigned)st) ? scn[threadIdx.x - st] : 0;
    __syncthreads();
    scn[threadIdx.x] += t;
    __syncthreads();
  }
  int excl = base + scn[threadIdx.x] - v;
  if ((int)threadIdx.x < nn) noffs[node0 + threadIdx.x] = excl;  // CSR start
  if (threadIdx.x == 0) noffs[min(node0 + 256, N)] = end;        // terminator
  hist[threadIdx.x] = excl;  // running cursor
  __syncthreads();
  for (int p = base + threadIdx.x; p < end; p += blockDim.x) {
    uint2 rec = binned[p];  // L2-hot re-read
    int dl = (int)(rec.x >> 24);
    int pos = atomicAdd(&hist[dl], 1);
    sedge[pos] = make_uint2(rec.x & 0xffffffu, (unsigned)(node0 + dl));
    float a = __uint_as_float(rec.y);
    float e0[ED];
#pragma unroll
    for (int j = 0; j < ED; ++j) e0[j] = fmaf(a, We[j], be[j]);
    *reinterpret_cast<uint4*>(e + (size_t)pos * ED) = pack8(e0);
  }
}

// ---------- layer kernels ----------

// edge MLP via precomputed projections — pure streaming, no scan/atomics:
// ne = relu(zs[src]+zd[dst]+e@W3); e += ne
__global__ void k_edge(const u16* __restrict__ zs,
                       const u16* __restrict__ zd,
                       u16* __restrict__ e,
                       u16* __restrict__ ne,
                       const uint2* __restrict__ sedge,
                       const float* __restrict__ W3,  // [ED][ED]
                       int E) {
  int i = xcd_swizzle(blockIdx.x, gridDim.x) * blockDim.x + threadIdx.x;
  if (i >= E) return;
  uint2 sd = sedge[i];
  float zsv[ED], zdv[ED], ein[ED], acc[ED];
  cvt8(*reinterpret_cast<const uint4*>(zs + (size_t)sd.x * ED), zsv);
  cvt8(*reinterpret_cast<const uint4*>(zd + (size_t)sd.y * ED), zdv);
  cvt8(*reinterpret_cast<const uint4*>(e + (size_t)i * ED), ein);
#pragma unroll
  for (int j = 0; j < ED; ++j) acc[j] = zsv[j] + zdv[j];
#pragma unroll
  for (int k = 0; k < ED; ++k)
#pragma unroll
    for (int j = 0; j < ED; ++j)
      acc[j] = fmaf(ein[k], W3[k * ED + j], acc[j]);
#pragma unroll
  for (int j = 0; j < ED; ++j) acc[j] = fmaxf(acc[j], 0.0f);
  *reinterpret_cast<uint4*>(ne + (size_t)i * ED) = pack8(acc);
  float eo[ED];
#pragma unroll
  for (int j = 0; j < ED; ++j) eo[j] = ein[j] + acc[j];
  *reinterpret_cast<uint4*>(e + (size_t)i * ED) = pack8(eo);
}

// node MLP: agg = sum of this node's CSR segment of ne; h += relu([h,agg]@W+b);
// emits next-layer zs/zd. Weights uniform (SGPR broadcast).
__global__ void k_node(u16* __restrict__ h,
                       const u16* __restrict__ ne,
                       const int* __restrict__ noffs,
                       const float* __restrict__ W,     // [(ND+ED)][ND]
                       const float* __restrict__ b,     // [ND]
                       const float* __restrict__ Wen,   // [72][ED] next layer
                       const float* __restrict__ ben,   // [ED] next layer
                       u16* __restrict__ zs, u16* __restrict__ zd,
                       int N) {
  int n = xcd_swizzle(blockIdx.x, gridDim.x) * blockDim.x + threadIdx.x;
  if (n >= N) return;
  int o0 = noffs[n], o1 = noffs[n + 1];
  float av[ED];
#pragma unroll
  for (int j = 0; j < ED; ++j) av[j] = 0.0f;
  int p = o0;
  for (; p + 3 < o1; p += 4) {
    uint4 r0 = *reinterpret_cast<const uint4*>(ne + (size_t)(p + 0) * ED);
    uint4 r1 = *reinterpret_cast<const uint4*>(ne + (size_t)(p + 1) * ED);
    uint4 r2 = *reinterpret_cast<const uint4*>(ne + (size_t)(p + 2) * ED);
    uint4 r3 = *reinterpret_cast<const uint4*>(ne + (size_t)(p + 3) * ED);
    float t0[ED], t1[ED], t2[ED], t3[ED];
    cvt8(r0, t0); cvt8(r1, t1); cvt8(r2, t2); cvt8(r3, t3);
#pragma unroll
    for (int j = 0; j < ED; ++j)
      av[j] += (t0[j] + t1[j]) + (t2[j] + t3[j]);
  }
  for (; p < o1; ++p) {
    float t[ED];
    cvt8(*reinterpret_cast<const uint4*>(ne + (size_t)p * ED), t);
#pragma unroll
    for (int j = 0; j < ED; ++j) av[j] += t[j];
  }
  float acc[ND];
#pragma unroll
  for (int j = 0; j < ND; ++j) acc[j] = b[j];
  uint4* h4 = reinterpret_cast<uint4*>(h + (size_t)n * ND);
  float hv[ND];
#pragma unroll
  for (int q = 0; q < 4; ++q) cvt8(h4[q], &hv[q * 8]);
#pragma unroll
  for (int k = 0; k < ND; ++k)
#pragma unroll
    for (int j = 0; j < ND; ++j) acc[j] = fmaf(hv[k], W[k * ND + j], acc[j]);
#pragma unroll
  for (int k = 0; k < ED; ++k)
#pragma unroll
    for (int j = 0; j < ND; ++j) acc[j] = fmaf(av[k], W[(ND + k) * ND + j], acc[j]);
  float hn[ND];
#pragma unroll
  for (int k = 0; k < ND; ++k) {
    float o = hv[k] + fmaxf(acc[k], 0.0f);
    hn[k] = __uint_as_float((unsigned)f2bf(o) << 16);  // round as stored
  }
#pragma unroll
  for (int q = 0; q < 4; ++q) h4[q] = pack8(&hn[q * 8]);
  // next-layer projections (always needed: layers 0..NL-2 feed a next layer)
  float zsv[ED], zdv[ED];
#pragma unroll
  for (int j = 0; j < ED; ++j) { zsv[j] = 0.0f; zdv[j] = ben[j]; }
#pragma unroll
  for (int k = 0; k < ND; ++k)
#pragma unroll
    for (int j = 0; j < ED; ++j) {
      zsv[j] = fmaf(hn[k], Wen[k * ED + j], zsv[j]);
      zdv[j] = fmaf(hn[k], Wen[(ND + k) * ED + j], zdv[j]);
    }
  *reinterpret_cast<uint4*>(zs + (size_t)n * ED) = pack8(zsv);
  *reinterpret_cast<uint4*>(zd + (size_t)n * ED) = pack8(zdv);
}

// ---------- fused last layer + readout over candidates only ----------

__device__ __forceinline__ unsigned int enc_f32(float f) {
  unsigned int bits = __float_as_uint(f);
  return (bits & 0x80000000u) ? ~bits : (bits | 0x80000000u);
}
__device__ __forceinline__ float dec_f32(unsigned int u) {
  unsigned int bits = (u & 0x80000000u) ? (u ^ 0x80000000u) : ~u;
  return __uint_as_float(bits);
}

// Per candidate: walk node's CSR segment computing layer-3 edge messages on
// the fly, aggregate, node MLP in registers, emit logit + segment max.
// Touches only ~NC/N of the edge data; h/e never rewritten.
__global__ void k_cand(const u16* __restrict__ h,
                       const u16* __restrict__ e,
                       const u16* __restrict__ zs,
                       const u16* __restrict__ zd,
                       const uint2* __restrict__ sedge,
                       const int* __restrict__ noffs,
                       const int* __restrict__ cand,
                       const int* __restrict__ batch,
                       const float* __restrict__ W3,   // [ED][ED] layer 3
                       const float* __restrict__ Wn,   // [(ND+ED)][ND] layer 3
                       const float* __restrict__ bn,   // [ND] layer 3
                       const float* __restrict__ Wout, // [ND]
                       const float* __restrict__ bout, // [1]
                       float* __restrict__ logits,
                       int* __restrict__ seg,
                       unsigned int* __restrict__ mxu,  // pre-zeroed
                       int NC) {
  int c = blockIdx.x * blockDim.x + threadIdx.x;
  if (c >= NC) return;
  int n = cand[c];
  int o0 = noffs[n], o1 = noffs[n + 1];
  float zdv[ED];
  cvt8(*reinterpret_cast<const uint4*>(zd + (size_t)n * ED), zdv);
  float av[ED];
#pragma unroll
  for (int j = 0; j < ED; ++j) av[j] = 0.0f;
  for (int p = o0; p < o1; ++p) {
    unsigned s = sedge[p].x;
    float zsv[ED], ein[ED], acc[ED];
    cvt8(*reinterpret_cast<const uint4*>(zs + (size_t)s * ED), zsv);
    cvt8(*reinterpret_cast<const uint4*>(e + (size_t)p * ED), ein);
#pragma unroll
    for (int j = 0; j < ED; ++j) acc[j] = zsv[j] + zdv[j];
#pragma unroll
    for (int k = 0; k < ED; ++k)
#pragma unroll
      for (int j = 0; j < ED; ++j)
        acc[j] = fmaf(ein[k], W3[k * ED + j], acc[j]);
#pragma unroll
    for (int j = 0; j < ED; ++j) av[j] += fmaxf(acc[j], 0.0f);
  }
  float acc[ND];
#pragma unroll
  for (int j = 0; j < ND; ++j) acc[j] = bn[j];
  const uint4* h4 = reinterpret_cast<const uint4*>(h + (size_t)n * ND);
  float hv[ND];
#pragma unroll
  for (int q = 0; q < 4; ++q) cvt8(h4[q], &hv[q * 8]);
#pragma unroll
  for (int k = 0; k < ND; ++k)
#pragma unroll
    for (int j = 0; j < ND; ++j) acc[j] = fmaf(hv[k], Wn[k * ND + j], acc[j]);
#pragma unroll
  for (int k = 0; k < ED; ++k)
#pragma unroll
    for (int j = 0; j < ND; ++j) acc[j] = fmaf(av[k], Wn[(ND + k) * ND + j], acc[j]);
  float lg = bout[0];
#pragma unroll
  for (int k = 0; k < ND; ++k)
    lg = fmaf(hv[k] + fmaxf(acc[k], 0.0f), Wout[k], lg);
  logits[c] = lg;
  int g = batch[n];
  seg[c] = g;
  atomicMax(&mxu[g], enc_f32(lg));
}

__global__ void k_expsum(float* __restrict__ logits,
                         const int* __restrict__ seg,
                         const unsigned int* __restrict__ mxu,
                         float* __restrict__ sum,  // pre-zeroed
                         int NC) {
  int c = blockIdx.x * blockDim.x + threadIdx.x;
  if (c >= NC) return;
  int g = seg[c];
  float sh = logits[c] - dec_f32(mxu[g]);
  logits[c] = sh;
  atomicAdd(&sum[g], expf(sh));
}

__global__ void k_final(const float* __restrict__ shifted,
                        const int* __restrict__ seg,
                        const float* __restrict__ sum,
                        float* __restrict__ out, int NC) {
  int c = blockIdx.x * blockDim.x + threadIdx.x;
  if (c >= NC) return;
  out[c] = shifted[c] - logf(sum[seg[c]]);
}

// ---------- launch ----------

extern "C" void kernel_launch(void* const* d_in, const int* in_sizes, int n_in,
                              void* d_out, int out_size, void* d_ws, size_t ws_size,
                              hipStream_t stream) {
  const float* x       = (const float*)d_in[0];
  const float* ea      = (const float*)d_in[1];
  const float* Wn_in   = (const float*)d_in[2];
  const float* bn_in   = (const float*)d_in[3];
  const float* We_in   = (const float*)d_in[4];
  const float* be_in   = (const float*)d_in[5];
  const float* We_l    = (const float*)d_in[6];
  const float* be_l    = (const float*)d_in[7];
  const float* Wn_l    = (const float*)d_in[8];
  const float* bn_l    = (const float*)d_in[9];
  const float* Wout    = (const float*)d_in[10];
  const float* bout    = (const float*)d_in[11];
  const int* edge_index= (const int*)d_in[12];
  const int* batch     = (const int*)d_in[13];
  const int* cand      = (const int*)d_in[14];

  const int N  = in_sizes[13];
  const int E  = in_sizes[1];
  const int NC = in_sizes[14];
  const int nbc = (N + 255) >> 8;

  char* ws = (char*)d_ws;
  uint2* binned = (uint2*)ws; ws += (size_t)E * sizeof(uint2);
  uint2* sedge  = (uint2*)ws; ws += (size_t)E * sizeof(uint2);
  u16*   h      = (u16*)ws;   ws += (size_t)N * ND * sizeof(u16);
  u16*   e      = (u16*)ws;   ws += (size_t)E * ED * sizeof(u16);
  u16*   ne     = (u16*)ws;   ws += (size_t)E * ED * sizeof(u16);
  u16*   zs     = (u16*)ws;   ws += (size_t)N * ED * sizeof(u16);
  u16*   zd     = (u16*)ws;   ws += (size_t)N * ED * sizeof(u16);
  int*   noffs  = (int*)ws;   ws += ((size_t)N + 4) * sizeof(int);
  int*   bcnt   = (int*)ws;   ws += (size_t)NBC_MAX * sizeof(int);   // contiguous
  int*   cursor = (int*)ws;   ws += (size_t)NBC_MAX * sizeof(int);   // with bcnt
  int*   bbase  = (int*)ws;   ws += ((size_t)NBC_MAX + 4) * sizeof(int);
  float* logits = (float*)ws; ws += (size_t)NC * sizeof(float);
  int*   seg    = (int*)ws;   ws += (size_t)NC * sizeof(int);
  unsigned int* mxu = (unsigned int*)ws; ws += (size_t)NG * sizeof(unsigned int);
  float* sum    = (float*)ws; ws += (size_t)NG * sizeof(float);  // contiguous w/ mxu

  const int* srcp = edge_index;
  const int* dstp = edge_index + E;
  const int blk = 256;
  const size_t WE_STRIDE = (size_t)(2 * ND + ED) * ED;  // 72*8

  // binned two-phase counting sort (8-B packed records) + e0 + CSR offsets
  hipMemsetAsync(bcnt, 0, 2 * (size_t)NBC_MAX * sizeof(int), stream);  // bcnt+cursor
  k_chist<<<(E + CHUNK_H - 1) / CHUNK_H, 1024, 0, stream>>>(dstp, bcnt, E, nbc);
  k_cscan<<<1, NBC_MAX, 0, stream>>>(bcnt, bbase, nbc);
  k_binA<<<(E + CHUNK - 1) / CHUNK, 1024, 0, stream>>>(srcp, dstp, ea, bbase,
                                                       cursor, binned, E, nbc);
  k_binB<<<nbc, 256, 0, stream>>>(binned, bbase, sedge, e, noffs, We_in, be_in, N);

  k_init_h<<<(N + NBLK - 1) / NBLK, NBLK, 0, stream>>>(x, Wn_in, bn_in, We_l,
                                                       be_l, h, zs, zd, N);

  const int egrid = (E + blk - 1) / blk;
  const int ngrid = (N + NBLK - 1) / NBLK;
  // layers 0..NL-2 full; layer NL-1 fused into k_cand (candidates only)
  for (int l = 0; l < NL - 1; ++l) {
    const float* W3 = We_l + l * WE_STRIDE + (size_t)2 * ND * ED;
    const float* Wn = Wn_l + (size_t)l * (ND + ED) * ND;
    const float* bn = bn_l + (size_t)l * ND;
    k_edge<<<egrid, blk, 0, stream>>>(zs, zd, e, ne, sedge, W3, E);
    k_node<<<ngrid, NBLK, 0, stream>>>(
        h, ne, noffs, Wn, bn, We_l + (l + 1) * WE_STRIDE,
        be_l + (size_t)(l + 1) * ED, zs, zd, N);
  }

  hipMemsetAsync(mxu, 0, NG * (sizeof(unsigned int) + sizeof(float)), stream);
  {
    const int l = NL - 1;
    const float* W3 = We_l + l * WE_STRIDE + (size_t)2 * ND * ED;
    const float* Wn = Wn_l + (size_t)l * (ND + ED) * ND;
    const float* bn = bn_l + (size_t)l * ND;
    k_cand<<<(NC + NBLK - 1) / NBLK, NBLK, 0, stream>>>(
        h, e, zs, zd, sedge, noffs, cand, batch, W3, Wn, bn, Wout, bout,
        logits, seg, mxu, NC);
  }
  k_expsum<<<(NC + blk - 1) / blk, blk, 0, stream>>>(logits, seg, mxu, sum, NC);
  k_final<<<(NC + blk - 1) / blk, blk, 0, stream>>>(logits, seg, sum,
                                                    (float*)d_out, NC);
}